// Round 7
// baseline (163.794 us; speedup 1.0000x reference)
//
#include <hip/hip_runtime.h>

// B=64, K=8, H=W=128 (HW=16384). float32 in/out.
// out[0] = loss scalar; out[1..] = pred_perm (B,K,H,W) flat.
//
// 2-dispatch pipeline (cooperative launch is BROKEN in this harness -- r5/r6):
//   cost_kernel : 512 blocks (b*8+s), r2-verified register-accumulator streaming
//                 (2 quads/thread, acc[64], reduce-scatter epilogue) -> part[p][72].
//                 Then: threadfence + epoch counter atomicAdd; the LAST block of
//                 each batch (old&7==7 -- correct across graph replays, no reset
//                 needed) re-reads the batch's 8 partials (L2-hot) and runs the
//                 Held-Karp DP inside this dispatch, writing invtab[b][8] and
//                 loss_part[b]. No co-residency assumption: last block always runs.
//   copy_kernel : 512 blocks: PURE permuted row copy (reads invtab[p], one int);
//                 block 0 wave-sums loss_part[64] -> out[0] (single writer, no
//                 atomics, no zero-init ordering hazard).

#define BB 64
#define KK 8
#define HW 16384
#define SPANS 8      // spans (phase-1 blocks) per batch
#define SPAN 2048    // floats per span per row (2 quads per thread)
#define EPSF 1e-15f

// ---------- compile-time mask table: all 255 nonzero 8-bit masks, level-ordered by popcount ----------
struct MaskTab {
    unsigned char masks[255];
    int off[9];
};

constexpr MaskTab make_tab() {
    MaskTab t{};
    int idx = 0;
    for (int p = 1; p <= 8; ++p) {
        t.off[p - 1] = idx;
        for (int m = 1; m < 256; ++m) {
            int c = 0;
            for (int b = 0; b < 8; ++b) c += (m >> b) & 1;
            if (c == p) t.masks[idx++] = (unsigned char)m;
        }
    }
    t.off[8] = idx;
    return t;
}

__constant__ MaskTab kTab = make_tab();

__device__ int g_cnt[64];   // epoch counters: +8 per launch; (old&7)==7 marks last block

__device__ __forceinline__ float dot4(float4 t, float4 l) {
    return t.x * l.x + t.y * l.y + t.z * l.z + t.w * l.w;
}

__device__ __forceinline__ float4 log4(float4 a) {
    float4 r;
    r.x = __logf(a.x + EPSF); r.y = __logf(a.y + EPSF);
    r.z = __logf(a.z + EPSF); r.w = __logf(a.w + EPSF);
    return r;
}

// ---------- phase 1: cost partials + last-block-per-batch DP ----------
__global__ __launch_bounds__(256) void cost_kernel(const float* __restrict__ pred,
                                                   const float* __restrict__ aug,
                                                   float* __restrict__ part,      // [512][72]
                                                   float* __restrict__ loss_part, // [64]
                                                   int*   __restrict__ invtab)    // [64][8]
{
    __shared__ float red1[4][72];   // wave combine
    __shared__ int   islast;
    __shared__ float red[72];       // batch partial reduce (last block only)
    __shared__ float C[64];
    __shared__ float dp[256];
    __shared__ int   choice[256];

    const int p    = blockIdx.x;    // b*8 + s
    const int b    = p >> 3;
    const int s    = p & 7;
    const int tid  = threadIdx.x;
    const int wave = tid >> 6;
    const int lane = tid & 63;

    const size_t base = (size_t)b * (KK * HW);

    float acc[64];
#pragma unroll
    for (int v = 0; v < 64; ++v) acc[v] = 0.f;
    float ent[8];
#pragma unroll
    for (int j = 0; j < 8; ++j) ent[j] = 0.f;

#pragma unroll
    for (int it = 0; it < 2; ++it) {
        const int e = s * SPAN + (it * 256 + tid) * 4;   // element index within a row
        const float* pp = pred + base + e;
        const float* ap = aug  + base + e;

        float4 lp[8];
#pragma unroll
        for (int i = 0; i < 8; ++i)
            lp[i] = log4(*(const float4*)(pp + (size_t)i * HW));

#pragma unroll
        for (int j = 0; j < 8; ++j) {
            const float4 a  = *(const float4*)(ap + (size_t)j * HW);
            ent[j] += dot4(a, log4(a));
#pragma unroll
            for (int i = 0; i < 8; ++i)
                acc[i * 8 + j] += dot4(a, lp[i]);
        }
    }

    // --- wave reduce-scatter over the 64 cross accumulators (63 shuffles) ---
    // After round r (d=1<<r), live count halves; lane l ends with the wave-total
    // of original acc[bitrev6(l)].
#pragma unroll
    for (int r = 0; r < 6; ++r) {
        const int d    = 1 << r;
        const int half = 32 >> r;
        const bool hi  = (lane & d) != 0;
#pragma unroll
        for (int k = 0; k < half; ++k) {
            const float send = hi ? acc[k] : acc[k + half];
            const float recv = __shfl_xor(send, d);
            acc[k] = (hi ? acc[k + half] : acc[k]) + recv;
        }
    }

    // --- ent reduce: 3-round reduce-scatter over 8 values + 3 plain butterflies ---
#pragma unroll
    for (int r = 0; r < 3; ++r) {
        const int d    = 1 << r;
        const int half = 4 >> r;
        const bool hi  = (lane & d) != 0;
#pragma unroll
        for (int k = 0; k < half; ++k) {
            const float send = hi ? ent[k] : ent[k + half];
            const float recv = __shfl_xor(send, d);
            ent[k] = (hi ? ent[k + half] : ent[k]) + recv;
        }
    }
    float ev = ent[0];
    ev += __shfl_xor(ev, 8);
    ev += __shfl_xor(ev, 16);
    ev += __shfl_xor(ev, 32);
    // lane l holds ent_total[bitrev3(l & 7)]

    // --- combine the 4 waves via LDS, store 72 partials ---
    const int vidx = ((lane & 1) << 5) | ((lane & 2) << 3) | ((lane & 4) << 1) |
                     ((lane & 8) >> 1) | ((lane & 16) >> 3) | ((lane & 32) >> 5);
    red1[wave][vidx] = acc[0];
    if (lane < 8)
        red1[wave][64 + (((lane & 1) << 2) | (lane & 2) | ((lane & 4) >> 2))] = ev;
    __syncthreads();

    if (tid < 72) {
        const float ssum = red1[0][tid] + red1[1][tid] + red1[2][tid] + red1[3][tid];
        part[(size_t)p * 72 + tid] = ssum;   // part[i*8+j]=cross[i][j]; part[64+j]=ent[j]
    }
    __threadfence();                 // release: partials device-visible before counter bump
    __syncthreads();

    if (tid == 0) {
        const int old = atomicAdd(&g_cnt[b], 1);
        islast = ((old & 7) == 7);   // 8th arrival of THIS launch (epoch trick)
    }
    __syncthreads();
    if (!islast) return;
    __threadfence();                 // acquire: peers' partials visible

    // ---- last block of batch b: reduce 8 partials + Held-Karp DP ----
    const float* pb = part + (size_t)b * SPANS * 72;
    if (tid < 72) {
        float sv = 0.f;
#pragma unroll
        for (int c = 0; c < SPANS; ++c) sv += pb[c * 72 + tid];
        red[tid] = sv;
    }
    if (tid == 0) dp[0] = 0.f;
    __syncthreads();
    if (tid < 64) C[tid] = red[64 + (tid & 7)] - red[tid];
    __syncthreads();

    const int grp = tid >> 3;
    const int j   = tid & 7;
    for (int lvl = 1; lvl <= 8; ++lvl) {
        const int start = kTab.off[lvl - 1];
        const int end   = kTab.off[lvl];
        const float* Crow = &C[(lvl - 1) * 8];
        for (int bse = start; bse < end; bse += 32) {
            const int mi = bse + grp;
            if (mi < end) {
                const int M = kTab.masks[mi];
                float v  = 1e30f;
                int   bj = 0;
                if (M & (1 << j)) {
                    v  = dp[M ^ (1 << j)] + Crow[j];
                    bj = j;
                }
#pragma unroll
                for (int d = 1; d < 8; d <<= 1) {
                    const float ov = __shfl_xor(v, d);
                    const int   oj = __shfl_xor(bj, d);
                    if (ov < v) { v = ov; bj = oj; }
                }
                if (j == 0) { dp[M] = v; choice[M] = bj; }
            }
        }
        __syncthreads();
    }

    if (tid == 0) {
        int mask = 255;
        for (int r = 7; r >= 0; --r) {
            const int jj = choice[mask];
            invtab[b * 8 + jj] = r;    // column jj takes pred row r
            mask ^= 1 << jj;
        }
        loss_part[b] = dp[255];
    }
}

// ---------- phase 2: pure permuted copy + single-writer loss ----------
__global__ __launch_bounds__(256) void copy_kernel(const float* __restrict__ pred,
                                                   const float* __restrict__ loss_part,
                                                   const int*   __restrict__ invtab,
                                                   float* __restrict__ out)
{
    const int p   = blockIdx.x;   // b*8 + jcol
    const int b   = p >> 3;
    const int tid = threadIdx.x;

    if (p == 0 && tid < 64) {     // loss: one wave sums 64 batch values
        float lv = loss_part[tid];
#pragma unroll
        for (int d = 1; d < 64; d <<= 1) lv += __shfl_xor(lv, d);
        if (tid == 0) out[0] = lv * (1.0f / (16384.0f * 512.0f));
    }

    const int src_row = invtab[p];   // uniform per block
    const float* src  = pred + ((size_t)(b << 3) + src_row) * HW;
    float*      drow  = out + 1 + (size_t)p * HW;

#pragma unroll
    for (int m = 0; m < 16; ++m) {
        const int f = tid + 256 * m;              // quad index in [0,4096)
        const int e = 3 + 4 * f;
        if (f < 4095) {
            float4 v;
            v.x = src[e]; v.y = src[e + 1]; v.z = src[e + 2]; v.w = src[e + 3];
            *(float4*)(drow + e) = v;             // 16B-aligned
        } else {                                  // f==4095: head 3 + tail 1
            drow[0] = src[0]; drow[1] = src[1]; drow[2] = src[2];
            drow[16383] = src[16383];
        }
    }
}

extern "C" void kernel_launch(void* const* d_in, const int* in_sizes, int n_in,
                              void* d_out, int out_size, void* d_ws, size_t ws_size,
                              hipStream_t stream) {
    const float* pred = (const float*)d_in[0];
    const float* aug  = (const float*)d_in[1];
    float* out  = (float*)d_out;

    float* part      = (float*)d_ws;             // 512*72 floats
    float* loss_part = part + 512 * 72;          // 64 floats
    int*   invtab    = (int*)(loss_part + 64);   // 512 ints

    cost_kernel<<<dim3(BB * SPANS), dim3(256), 0, stream>>>(pred, aug, part, loss_part, invtab);
    copy_kernel<<<dim3(512), dim3(256), 0, stream>>>(pred, loss_part, invtab, out);
}

// Round 8
// 121.592 us; speedup vs baseline: 1.3471x; 1.3471x over previous
//
#include <hip/hip_runtime.h>

// B=64, K=8, H=W=128 (HW=16384). float32 in/out.
// out[0] = loss scalar; out[1..] = pred_perm (B,K,H,W) flat.
//
// 2-dispatch pipeline. Ground truth from r7: fixed overhead F~58us (timed
// re-poison fill + gaps), copy/permute ~20-22us, cost ~39us in ALL prior
// CU-side structures (16-stream gather / LDS-staged / dbuf). r7's 85us cost was
// regalloc pollution (VGPR=76 -> acc spilled) from merging DP+fences into it.
//
//   cost_kernel : 512 blocks, p -> (i = p>>6, b = p&63). Each block: ONE pred
//                 row (b,i) + the 8 aug rows of batch b (9 streams/thread,
//                 acc[8], ~70 VGPR, no spill). Decode clusters batch b's 8
//                 blocks at p === b (mod 64) -> same XCD under round-robin ->
//                 aug re-reads are XCD-local L2 hits (8 batches/XCD = 4MB = L2).
//                 ent[i] computed by block (b,i) on its own aug-i stream
//                 (wave-uniform j==i branch). Per-block 4KB phase rotation.
//                 Epilogue: verified 3-round reduce-scatter + LDS combine -> 9 floats.
//   permute_kernel: 512 blocks (b*8+jcol): direct C build from part (2 reads/
//                 thread), verified Held-Karp DP (redundant per block), verified
//                 permuted float4 row copy; one block per batch atomicAdds loss.

#define BB 64
#define KK 8
#define HW 16384
#define EPSF 1e-15f

// ---------- compile-time mask table: all 255 nonzero 8-bit masks, level-ordered by popcount ----------
struct MaskTab {
    unsigned char masks[255];
    int off[9];
};

constexpr MaskTab make_tab() {
    MaskTab t{};
    int idx = 0;
    for (int p = 1; p <= 8; ++p) {
        t.off[p - 1] = idx;
        for (int m = 1; m < 256; ++m) {
            int c = 0;
            for (int b = 0; b < 8; ++b) c += (m >> b) & 1;
            if (c == p) t.masks[idx++] = (unsigned char)m;
        }
    }
    t.off[8] = idx;
    return t;
}

__constant__ MaskTab kTab = make_tab();

__device__ __forceinline__ float dot4(float4 t, float4 l) {
    return t.x * l.x + t.y * l.y + t.z * l.z + t.w * l.w;
}

__device__ __forceinline__ float4 log4(float4 a) {
    float4 r;
    r.x = __logf(a.x + EPSF); r.y = __logf(a.y + EPSF);
    r.z = __logf(a.z + EPSF); r.w = __logf(a.w + EPSF);
    return r;
}

// ---------- phase 1: one pred row per block, 8 aug streams, acc[8] ----------
// part[p*9 + j] = cross[i][j] (p = i*64+b), part[p*9+8] = ent[i] of batch b.
__global__ __launch_bounds__(256) void cost_kernel(const float* __restrict__ pred,
                                                   const float* __restrict__ aug,
                                                   float* __restrict__ part,   // [512][9]
                                                   float* __restrict__ out)
{
    __shared__ float red[4][9];

    const int p    = blockIdx.x;
    const int i    = p >> 6;        // pred row index 0..7
    const int b    = p & 63;        // batch -> p === b (mod 64): same-XCD clustering
    const int tid  = threadIdx.x;
    const int wave = tid >> 6;
    const int lane = tid & 63;

    if (p == 0 && tid == 0) out[0] = 0.f;   // loss accumulator init (pre-atomics, r2-proven)

    const float* prow  = pred + ((size_t)b * KK + i) * HW;
    const float* abase = aug  + (size_t)b * KK * HW;

    float acc[8];
#pragma unroll
    for (int j = 0; j < 8; ++j) acc[j] = 0.f;
    float eacc = 0.f;

    const int rot = p & 15;         // 4KB phase rotation (decorrelate blocks)

    for (int m = 0; m < 16; ++m) {
        const int mm = (m + rot) & 15;
        const int e  = (tid + 256 * mm) * 4;    // float offset within the row

        const float4 pq = *(const float4*)(prow + e);
        const float4 la = log4(pq);

#pragma unroll
        for (int j = 0; j < 8; ++j) {
            const float4 a = *(const float4*)(abase + (size_t)j * HW + e);
            acc[j] += dot4(a, la);
            if (j == i) eacc += dot4(a, log4(a));   // block-uniform branch
        }
    }

    // --- 3-round reduce-scatter over acc[8] (verified r2 ent pattern) ---
#pragma unroll
    for (int r = 0; r < 3; ++r) {
        const int d    = 1 << r;
        const int half = 4 >> r;
        const bool hi  = (lane & d) != 0;
#pragma unroll
        for (int k = 0; k < half; ++k) {
            const float send = hi ? acc[k] : acc[k + half];
            const float recv = __shfl_xor(send, d);
            acc[k] = (hi ? acc[k + half] : acc[k]) + recv;
        }
    }
    float av = acc[0];
    av += __shfl_xor(av, 8);
    av += __shfl_xor(av, 16);
    av += __shfl_xor(av, 32);
    // lane l holds cross_total[bitrev3(l & 7)]

    // --- ent: full 6-round butterfly ---
#pragma unroll
    for (int d = 1; d < 64; d <<= 1) eacc += __shfl_xor(eacc, d);

    // --- combine the 4 waves via LDS, store 9 partials ---
    if (lane < 8)
        red[wave][((lane & 1) << 2) | (lane & 2) | ((lane & 4) >> 2)] = av;
    if (lane == 0)
        red[wave][8] = eacc;
    __syncthreads();

    if (tid < 9)
        part[(size_t)p * 9 + tid] = red[0][tid] + red[1][tid] + red[2][tid] + red[3][tid];
}

// ---------- phase 2: direct C build + DP + permuted copy (512 blocks) ----------
// block p2 = b*8 + jcol. C[i*8+j] = ent[j] - cross[i][j] built from part directly.
__global__ __launch_bounds__(256) void permute_kernel(const float* __restrict__ pred,
                                                      const float* __restrict__ part,
                                                      float* __restrict__ out)
{
    __shared__ float C[64];     // C[i*8+j] = ent[j] - cross[i][j] (unscaled)
    __shared__ float dp[256];
    __shared__ int   choice[256];
    __shared__ int   inv8[8];   // col -> src row

    const int p    = blockIdx.x;   // pair = b*8 + jcol
    const int b    = p >> 3;
    const int tid  = threadIdx.x;

    if (tid < 64) {
        const int ii = tid >> 3, jj = tid & 7;
        const float cross = part[((size_t)ii * 64 + b) * 9 + jj];
        const float entj  = part[((size_t)jj * 64 + b) * 9 + 8];
        C[tid] = entj - cross;
    }
    if (tid == 0) dp[0] = 0.f;
    __syncthreads();

    // --- Held-Karp DP over 255 masks, level-ordered; 32 mask slots per pass ---
    const int grp = tid >> 3;
    const int j   = tid & 7;
    for (int lvl = 1; lvl <= 8; ++lvl) {
        const int start = kTab.off[lvl - 1];
        const int end   = kTab.off[lvl];
        const float* Crow = &C[(lvl - 1) * 8];
        for (int bse = start; bse < end; bse += 32) {
            const int mi = bse + grp;
            if (mi < end) {
                const int M = kTab.masks[mi];
                float v  = 1e30f;
                int   bj = 0;
                if (M & (1 << j)) {
                    v  = dp[M ^ (1 << j)] + Crow[j];
                    bj = j;
                }
#pragma unroll
                for (int d = 1; d < 8; d <<= 1) {
                    const float ov = __shfl_xor(v, d);
                    const int   oj = __shfl_xor(bj, d);
                    if (ov < v) { v = ov; bj = oj; }
                }
                if (j == 0) { dp[M] = v; choice[M] = bj; }
            }
        }
        __syncthreads();
    }

    if (tid == 0) {
        int mask = 255;
        for (int r = 7; r >= 0; --r) {
            const int jj = choice[mask];
            inv8[jj] = r;              // column jj takes pred row r
            mask ^= 1 << jj;
        }
        if ((p & 7) == 0)              // one designated block per batch
            atomicAdd(out, dp[255] * (1.0f / (16384.0f * 512.0f)));
    }
    __syncthreads();

    // --- permuted copy of the full row (16384 elements = 4096 quads) ---
    const int src_row = inv8[p & 7];   // uniform per block
    const float* src  = pred + ((size_t)(b << 3) + src_row) * HW;
    float*      drow  = out + 1 + (size_t)p * HW;

#pragma unroll
    for (int m = 0; m < 16; ++m) {
        const int f = tid + 256 * m;              // quad index in [0,4096)
        const int e = 3 + 4 * f;
        if (f < 4095) {
            float4 v;
            v.x = src[e]; v.y = src[e + 1]; v.z = src[e + 2]; v.w = src[e + 3];
            *(float4*)(drow + e) = v;             // 16B-aligned
        } else {                                  // f==4095: head 3 + tail 1
            drow[0] = src[0]; drow[1] = src[1]; drow[2] = src[2];
            drow[16383] = src[16383];
        }
    }
}

extern "C" void kernel_launch(void* const* d_in, const int* in_sizes, int n_in,
                              void* d_out, int out_size, void* d_ws, size_t ws_size,
                              hipStream_t stream) {
    const float* pred = (const float*)d_in[0];
    const float* aug  = (const float*)d_in[1];
    float* out  = (float*)d_out;
    float* part = (float*)d_ws;                      // 512*9 floats

    cost_kernel<<<dim3(512), dim3(256), 0, stream>>>(pred, aug, part, out);
    permute_kernel<<<dim3(512), dim3(256), 0, stream>>>(pred, part, out);
}